// Round 3
// baseline (84.143 us; speedup 1.0000x reference)
//
#include <hip/hip_runtime.h>
#include <hip/hip_bf16.h>
#include <cstdint>

// Problem constants: B=1024, S=8, H=16, DK=DV=32, D=512
#define NB 1024
#define ND 512
#define NM 8192  // B*S rows

typedef __attribute__((ext_vector_type(8))) short short8;
typedef __attribute__((ext_vector_type(8))) __bf16 bf16x8;
typedef __attribute__((ext_vector_type(4))) float f32x4;
typedef __attribute__((ext_vector_type(4))) unsigned short ushort4v;

__device__ __forceinline__ unsigned short f2bf(float f) {
  uint32_t x = __builtin_bit_cast(uint32_t, f);
  x += 0x7fffu + ((x >> 16) & 1u);  // RNE
  return (unsigned short)(x >> 16);
}
__device__ __forceinline__ float bf2f(unsigned short u) {
  return __builtin_bit_cast(float, (uint32_t)u << 16);
}
__device__ __forceinline__ f32x4 mfma16(short8 a, short8 b, f32x4 c) {
  return __builtin_amdgcn_mfma_f32_16x16x32_bf16(
      __builtin_bit_cast(bf16x8, a), __builtin_bit_cast(bf16x8, b), c, 0, 0, 0);
}
// async global->LDS, 16B per lane; lds base must be wave-uniform (m104)
__device__ __forceinline__ void gl_lds16(const unsigned short* g, unsigned short* lds) {
  __builtin_amdgcn_global_load_lds(
      (const __attribute__((address_space(1))) unsigned int*)g,
      (__attribute__((address_space(3))) unsigned int*)lds, 16, 0, 0);
}

// ---- fp32 -> bf16 pre-convert: Q,K,V (3 x 4194304) + Wq,Wk,Wv,Wo (4 x 262144)
__global__ __launch_bounds__(256) void convert_kernel(
    const float* __restrict__ Q, const float* __restrict__ K, const float* __restrict__ V,
    const float* __restrict__ Wq, const float* __restrict__ Wk, const float* __restrict__ Wv,
    const float* __restrict__ Wo,
    unsigned short* __restrict__ Qb, unsigned short* __restrict__ Kb,
    unsigned short* __restrict__ Vb, unsigned short* __restrict__ Wqb,
    unsigned short* __restrict__ Wkb, unsigned short* __restrict__ Wvb,
    unsigned short* __restrict__ Wob) {
  const int idx = blockIdx.x * 256 + threadIdx.x;  // one 8-elem chunk each
  const float* src;
  unsigned short* dst;
  int off;
  if (idx < 3 * 524288) {
    const int sel = idx >> 19, o = idx & 524287;
    src = sel == 0 ? Q : sel == 1 ? K : V;
    dst = sel == 0 ? Qb : sel == 1 ? Kb : Vb;
    off = o * 8;
  } else {
    const int w = idx - 3 * 524288;
    const int sel = w >> 15, o = w & 32767;
    src = sel == 0 ? Wq : sel == 1 ? Wk : sel == 2 ? Wv : Wo;
    dst = sel == 0 ? Wqb : sel == 1 ? Wkb : sel == 2 ? Wvb : Wob;
    off = o * 8;
  }
  const float4 a = ((const float4*)(src + off))[0];
  const float4 b = ((const float4*)(src + off))[1];
  short8 r;
  r[0] = (short)f2bf(a.x); r[1] = (short)f2bf(a.y);
  r[2] = (short)f2bf(a.z); r[3] = (short)f2bf(a.w);
  r[4] = (short)f2bf(b.x); r[5] = (short)f2bf(b.y);
  r[6] = (short)f2bf(b.z); r[7] = (short)f2bf(b.w);
  *(short8*)(dst + off) = r;
}

// ---- GEMM tile core (m97 structure): C[m][n] = A[m][:] . W[n][:] (+bias[, +resid])
// 128x128 tile, BK=64, 512 threads (8 waves 2x4, wave tile 64x32, acc 4x2).
// Staging: global_load_lds width=16, linear LDS [128][64] (2-phase; conflicts hidden).
// MODE 0: C = bf16(acc + bias).  MODE 1: C = f32(acc + bias + resid).
template <int MODE>
__device__ __forceinline__ void gemm_tile(const unsigned short* __restrict__ A,
                                          const unsigned short* __restrict__ W,
                                          const float* __restrict__ bias,
                                          const float* __restrict__ resid,
                                          void* __restrict__ C, int mBase, int nBase) {
  __shared__ unsigned short As[128 * 64];
  __shared__ unsigned short Bs[128 * 64];
  const int tid = threadIdx.x;
  const int lane = tid & 63, wid = tid >> 6;
  const int wm = wid >> 2, wn = wid & 3;
  const int l15 = lane & 15, l4 = lane >> 4;
  // staging geometry: wave w covers rows [w*16, w*16+16) via 2 issues of 8 rows;
  // lane l -> row +her (l>>3), col (l&7)*8  (matches linear lane order, m104)
  const int srow = wid * 16;
  const int lrow = lane >> 3, lcol = (lane & 7) * 8;
  f32x4 acc[4][2] = {};

  for (int kt = 0; kt < 8; ++kt) {
    const int kBase = kt * 64;
#pragma unroll
    for (int i = 0; i < 2; ++i) {
      const int r0 = srow + i * 8;
      gl_lds16(A + (size_t)(mBase + r0 + lrow) * ND + kBase + lcol, &As[r0 * 64]);
      gl_lds16(W + (size_t)(nBase + r0 + lrow) * ND + kBase + lcol, &Bs[r0 * 64]);
    }
    __syncthreads();  // drains vmcnt+lgkmcnt before barrier (compiler-emitted)
#pragma unroll
    for (int kk = 0; kk < 2; ++kk) {
      short8 af[4], bf4[2];
#pragma unroll
      for (int m = 0; m < 4; ++m)
        af[m] = *(const short8*)&As[(wm * 64 + m * 16 + l15) * 64 + kk * 32 + l4 * 8];
#pragma unroll
      for (int n = 0; n < 2; ++n)
        bf4[n] = *(const short8*)&Bs[(wn * 32 + n * 16 + l15) * 64 + kk * 32 + l4 * 8];
#pragma unroll
      for (int m = 0; m < 4; ++m)
#pragma unroll
        for (int n = 0; n < 2; ++n)
          acc[m][n] = mfma16(af[m], bf4[n], acc[m][n]);
    }
    __syncthreads();
  }

  // C/D layout: col = lane&15, row = (lane>>4)*4 + r  [verified rounds 1-2]
#pragma unroll
  for (int m = 0; m < 4; ++m)
#pragma unroll
    for (int n = 0; n < 2; ++n) {
      const int gn = nBase + wn * 32 + n * 16 + l15;
      const float bb = bias ? bias[gn] : 0.f;
#pragma unroll
      for (int r4 = 0; r4 < 4; ++r4) {
        const int gm = mBase + wm * 64 + m * 16 + l4 * 4 + r4;
        float val = acc[m][n][r4] + bb;
        if (MODE == 0) {
          ((unsigned short*)C)[(size_t)gm * ND + gn] = f2bf(val);
        } else {
          val += resid[(size_t)gm * ND + gn];
          ((float*)C)[(size_t)gm * ND + gn] = val;
        }
      }
    }
}

// Fused QKV projection: 1-D grid 768 (= 8 XCDs x 96), bijective chunked swizzle.
__global__ __launch_bounds__(512) void gemm_qkv(
    const unsigned short* __restrict__ Qb, const unsigned short* __restrict__ Kb,
    const unsigned short* __restrict__ Vb, const unsigned short* __restrict__ Wqb,
    const unsigned short* __restrict__ Wkb, const unsigned short* __restrict__ Wvb,
    const float* __restrict__ bq, const float* __restrict__ bk,
    const float* __restrict__ bv, unsigned short* __restrict__ qo,
    unsigned short* __restrict__ ko, unsigned short* __restrict__ vo) {
  const int bid = blockIdx.x;
  const int lid = (bid & 7) * 96 + (bid >> 3);  // each XCD: 8 consecutive m-panels
  const int by = lid / 12, bx = lid % 12;
  const int seg = bx >> 2, nloc = bx & 3;
  const unsigned short* A = seg == 0 ? Qb : seg == 1 ? Kb : Vb;
  const unsigned short* W = seg == 0 ? Wqb : seg == 1 ? Wkb : Wvb;
  const float* bias = seg == 0 ? bq : seg == 1 ? bk : bv;
  unsigned short* C = seg == 0 ? qo : seg == 1 ? ko : vo;
  gemm_tile<0>(A, W, bias, nullptr, C, by * 128, nloc * 128);
}

// Wo GEMM + bias + residual(Q): 1-D grid 256 (= 8 x 32), chunked swizzle.
__global__ __launch_bounds__(512) void gemm_wo(const unsigned short* __restrict__ ctx,
                                               const unsigned short* __restrict__ Wob,
                                               const float* __restrict__ bo,
                                               const float* __restrict__ Qres,
                                               float* __restrict__ out) {
  const int bid = blockIdx.x;
  const int lid = (bid & 7) * 32 + (bid >> 3);
  const int by = lid >> 2, bx = lid & 3;
  gemm_tile<1>(ctx, Wob, bo, Qres, out, by * 128, bx * 128);
}

// ---- attention: one wave per (b,h); lane -> (i=lane>>3, j=lane&7)
__global__ __launch_bounds__(256) void attn_kernel(
    const unsigned short* __restrict__ q, const unsigned short* __restrict__ k,
    const unsigned short* __restrict__ v, const int* __restrict__ mask,
    const float* __restrict__ hyper, float* __restrict__ wout,
    unsigned short* __restrict__ ctx) {
  const int tid = threadIdx.x;
  const int wid = tid >> 6, lane = tid & 63;
  const int t = blockIdx.x * 4 + wid;  // b*16 + h
  const int b = t >> 4, h = t & 15;
  const int i = lane >> 3, j = lane & 7;

  const unsigned short* qrow = q + (size_t)(b * 8 + i) * ND + h * 32;
  const unsigned short* krow = k + (size_t)(b * 8 + j) * ND + h * 32;
  float dot = 0.f;
#pragma unroll
  for (int c = 0; c < 4; ++c) {
    const short8 qv = ((const short8*)qrow)[c];
    const short8 kv = ((const short8*)krow)[c];
#pragma unroll
    for (int e = 0; e < 8; ++e)
      dot += bf2f((unsigned short)qv[e]) * bf2f((unsigned short)kv[e]);
  }
  float score = dot * 0.17677669529663687f;  // 1/sqrt(32)
  if (mask[b * 64 + i * 8 + j]) score = -1e9f;

  float mx = score;
#pragma unroll
  for (int o = 4; o; o >>= 1) mx = fmaxf(mx, __shfl_xor(mx, o, 8));
  const float e = __expf(score - mx);
  float sm = e;
#pragma unroll
  for (int o = 4; o; o >>= 1) sm += __shfl_xor(sm, o, 8);
  const float w = e / sm;
  wout[(size_t)t * 64 + lane] = w;

  const int d0 = (lane & 7) * 4;
  float c0 = 0, c1 = 0, c2 = 0, c3 = 0;
#pragma unroll
  for (int jj = 0; jj < 8; ++jj) {
    const float wj = __shfl(w, jj, 8);
    const ushort4v vv = *(const ushort4v*)(v + (size_t)(b * 8 + jj) * ND + h * 32 + d0);
    c0 += wj * bf2f(vv[0]); c1 += wj * bf2f(vv[1]);
    c2 += wj * bf2f(vv[2]); c3 += wj * bf2f(vv[3]);
  }
  const float4 hv = *(const float4*)(hyper + (size_t)b * 4096 + h * 256 + i * 32 + d0);
  ushort4v co;
  co[0] = f2bf(c0 * hv.x); co[1] = f2bf(c1 * hv.y);
  co[2] = f2bf(c2 * hv.z); co[3] = f2bf(c3 * hv.w);
  *(ushort4v*)(ctx + (size_t)(b * 8 + i) * ND + h * 32 + d0) = co;
}

// ---- in-place: io = LN(io) * g + b  (residual+bias already fused into gemm_wo)
__global__ __launch_bounds__(256) void ln_kernel(float* __restrict__ io,
                                                 const float* __restrict__ g,
                                                 const float* __restrict__ be) {
  const int tid = threadIdx.x, wid = tid >> 6, lane = tid & 63;
  const size_t row = (size_t)blockIdx.x * 4 + wid;
  float* prow = io + row * ND + lane * 8;
  float4 x0 = ((float4*)prow)[0], x1 = ((float4*)prow)[1];
  float s = x0.x + x0.y + x0.z + x0.w + x1.x + x1.y + x1.z + x1.w;
  float sq = x0.x * x0.x + x0.y * x0.y + x0.z * x0.z + x0.w * x0.w +
             x1.x * x1.x + x1.y * x1.y + x1.z * x1.z + x1.w * x1.w;
#pragma unroll
  for (int o = 32; o; o >>= 1) {
    s += __shfl_xor(s, o, 64);
    sq += __shfl_xor(sq, o, 64);
  }
  const float mu = s * (1.f / 512.f);
  const float inv = rsqrtf(sq * (1.f / 512.f) - mu * mu + 1e-5f);
  const float4 g0 = ((const float4*)(g + lane * 8))[0];
  const float4 g1 = ((const float4*)(g + lane * 8))[1];
  const float4 e0 = ((const float4*)(be + lane * 8))[0];
  const float4 e1 = ((const float4*)(be + lane * 8))[1];
  float4 o0, o1;
  o0.x = (x0.x - mu) * inv * g0.x + e0.x; o0.y = (x0.y - mu) * inv * g0.y + e0.y;
  o0.z = (x0.z - mu) * inv * g0.z + e0.z; o0.w = (x0.w - mu) * inv * g0.w + e0.w;
  o1.x = (x1.x - mu) * inv * g1.x + e1.x; o1.y = (x1.y - mu) * inv * g1.y + e1.y;
  o1.z = (x1.z - mu) * inv * g1.z + e1.z; o1.w = (x1.w - mu) * inv * g1.w + e1.w;
  ((float4*)prow)[0] = o0;
  ((float4*)prow)[1] = o1;
}

extern "C" void kernel_launch(void* const* d_in, const int* in_sizes, int n_in,
                              void* d_out, int out_size, void* d_ws, size_t ws_size,
                              hipStream_t stream) {
  const float* Q = (const float*)d_in[0];
  const float* K = (const float*)d_in[1];
  const float* V = (const float*)d_in[2];
  const int* msk = (const int*)d_in[3];
  const float* hyper = (const float*)d_in[4];
  const float* Wq = (const float*)d_in[5];
  const float* bq = (const float*)d_in[6];
  const float* Wk = (const float*)d_in[7];
  const float* bk = (const float*)d_in[8];
  const float* Wv = (const float*)d_in[9];
  const float* bv = (const float*)d_in[10];
  const float* Wo = (const float*)d_in[11];
  const float* bo = (const float*)d_in[12];
  const float* lg = (const float*)d_in[13];
  const float* lb = (const float*)d_in[14];

  float* out = (float*)d_out;           // [8192,512] fp32
  float* wout = out + (size_t)NM * ND;  // [1024,16,8,8] fp32

  const size_t MAT = (size_t)NM * ND;  // elements
  unsigned short* Qb = (unsigned short*)d_ws;
  unsigned short* Kb = Qb + MAT;
  unsigned short* Vb = Kb + MAT;
  unsigned short* qb = Vb + MAT;
  unsigned short* kb = qb + MAT;
  unsigned short* vb = kb + MAT;
  unsigned short* ctxb = vb + MAT;
  unsigned short* Wqb = ctxb + MAT;
  unsigned short* Wkb = Wqb + (size_t)ND * ND;
  unsigned short* Wvb = Wkb + (size_t)ND * ND;
  unsigned short* Wob = Wvb + (size_t)ND * ND;

  convert_kernel<<<6656, 256, 0, stream>>>(Q, K, V, Wq, Wk, Wv, Wo,
                                           Qb, Kb, Vb, Wqb, Wkb, Wvb, Wob);
  gemm_qkv<<<768, 512, 0, stream>>>(Qb, Kb, Vb, Wqb, Wkb, Wvb,
                                    bq, bk, bv, qb, kb, vb);
  attn_kernel<<<4096, 256, 0, stream>>>(qb, kb, vb, msk, hyper, wout, ctxb);
  gemm_wo<<<256, 512, 0, stream>>>(ctxb, Wob, bo, Q, out);
  ln_kernel<<<2048, 256, 0, stream>>>(out, lg, lb);
}

// Round 4
// 74.638 us; speedup vs baseline: 1.1274x; 1.1274x over previous
//
#include <hip/hip_runtime.h>
#include <hip/hip_bf16.h>
#include <cstdint>

// Problem constants: B=1024, S=8, H=16, DK=DV=32, D=512
#define NB 1024
#define ND 512
#define NM 8192  // B*S rows

typedef __attribute__((ext_vector_type(8))) short short8;
typedef __attribute__((ext_vector_type(8))) __bf16 bf16x8;
typedef __attribute__((ext_vector_type(4))) float f32x4;
typedef __attribute__((ext_vector_type(4))) unsigned short ushort4v;

__device__ __forceinline__ unsigned short f2bf(float f) {
  uint32_t x = __builtin_bit_cast(uint32_t, f);
  x += 0x7fffu + ((x >> 16) & 1u);  // RNE
  return (unsigned short)(x >> 16);
}
__device__ __forceinline__ float bf2f(unsigned short u) {
  return __builtin_bit_cast(float, (uint32_t)u << 16);
}
__device__ __forceinline__ f32x4 mfma16(short8 a, short8 b, f32x4 c) {
  return __builtin_amdgcn_mfma_f32_16x16x32_bf16(
      __builtin_bit_cast(bf16x8, a), __builtin_bit_cast(bf16x8, b), c, 0, 0, 0);
}

// ---- fp32 -> bf16 pre-convert: weights only (Wq,Wk,Wv,Wo: 4 x 262144)
__global__ __launch_bounds__(256) void convert_w(
    const float* __restrict__ Wq, const float* __restrict__ Wk,
    const float* __restrict__ Wv, const float* __restrict__ Wo,
    unsigned short* __restrict__ Wqb, unsigned short* __restrict__ Wkb,
    unsigned short* __restrict__ Wvb, unsigned short* __restrict__ Wob) {
  const int idx = blockIdx.x * 256 + threadIdx.x;  // one 8-elem chunk each
  const int sel = idx >> 15, o = (idx & 32767) * 8;
  const float* src = sel == 0 ? Wq : sel == 1 ? Wk : sel == 2 ? Wv : Wo;
  unsigned short* dst = sel == 0 ? Wqb : sel == 1 ? Wkb : sel == 2 ? Wvb : Wob;
  const float4 a = ((const float4*)(src + o))[0];
  const float4 b = ((const float4*)(src + o))[1];
  short8 r;
  r[0] = (short)f2bf(a.x); r[1] = (short)f2bf(a.y);
  r[2] = (short)f2bf(a.z); r[3] = (short)f2bf(a.w);
  r[4] = (short)f2bf(b.x); r[5] = (short)f2bf(b.y);
  r[6] = (short)f2bf(b.z); r[7] = (short)f2bf(b.w);
  *(short8*)(dst + o) = r;
}

// ---- GEMM tile core (R2 reg-staged structure, proven 80.1us):
// C[m][n] = A[m][:] . W[n][:] (+bias[, +resid])
// 128x128 tile, BK=64, 512 threads (8 waves 2x4, wave tile 64x32, acc 4x2).
// LDS XOR-swizzle byte ^= (row&7)<<4 on write AND read -> uniform bank spread.
// A_F32: stage A from f32 with in-reg cvt (fuses the convert pass).
// MODE 0: C = bf16(acc + bias).  MODE 1: C = f32(acc + bias + resid).
template <bool A_F32, int MODE>
__device__ __forceinline__ void gemm_tile(const void* __restrict__ A,
                                          const unsigned short* __restrict__ W,
                                          const float* __restrict__ bias,
                                          const float* __restrict__ resid,
                                          void* __restrict__ C, int mBase, int nBase) {
  __shared__ unsigned short As[128 * 64];
  __shared__ unsigned short Bs[128 * 64];
  const int tid = threadIdx.x;
  const int lane = tid & 63, wid = tid >> 6;
  const int wm = wid >> 2, wn = wid & 3;
  const int l15 = lane & 15, l4 = lane >> 4;
  f32x4 acc[4][2] = {};

  for (int kt = 0; kt < 8; ++kt) {
    const int kBase = kt * 64;
#pragma unroll
    for (int i = 0; i < 2; ++i) {
      const int Lb = i * 8192 + tid * 16;  // logical byte offset in 128x64 bf16 tile
      const int r = Lb >> 7;
      const int ce = (Lb & 127) >> 1;  // element col in [0,64)
      const int P = Lb ^ ((r & 7) << 4);
      short8 av;
      if (A_F32) {
        const float* src = (const float*)A + (size_t)(mBase + r) * ND + kBase + ce;
        const float4 a = ((const float4*)src)[0];
        const float4 b = ((const float4*)src)[1];
        av[0] = (short)f2bf(a.x); av[1] = (short)f2bf(a.y);
        av[2] = (short)f2bf(a.z); av[3] = (short)f2bf(a.w);
        av[4] = (short)f2bf(b.x); av[5] = (short)f2bf(b.y);
        av[6] = (short)f2bf(b.z); av[7] = (short)f2bf(b.w);
      } else {
        av = *(const short8*)((const unsigned short*)A +
                              (size_t)(mBase + r) * ND + kBase + ce);
      }
      const short8 wv = *(const short8*)(W + (size_t)(nBase + r) * ND + kBase + ce);
      *(short8*)((char*)As + P) = av;
      *(short8*)((char*)Bs + P) = wv;
    }
    __syncthreads();
#pragma unroll
    for (int kk = 0; kk < 2; ++kk) {
      short8 af[4], bf4[2];
#pragma unroll
      for (int m = 0; m < 4; ++m) {
        const int r = wm * 64 + m * 16 + l15;
        const int Lb = r * 128 + kk * 64 + l4 * 16;
        af[m] = *(const short8*)((char*)As + (Lb ^ ((r & 7) << 4)));
      }
#pragma unroll
      for (int n = 0; n < 2; ++n) {
        const int r = wn * 32 + n * 16 + l15;
        const int Lb = r * 128 + kk * 64 + l4 * 16;
        bf4[n] = *(const short8*)((char*)Bs + (Lb ^ ((r & 7) << 4)));
      }
#pragma unroll
      for (int m = 0; m < 4; ++m)
#pragma unroll
        for (int n = 0; n < 2; ++n)
          acc[m][n] = mfma16(af[m], bf4[n], acc[m][n]);
    }
    __syncthreads();
  }

  // C/D layout: col = lane&15, row = (lane>>4)*4 + r  [verified rounds 1-3]
#pragma unroll
  for (int m = 0; m < 4; ++m)
#pragma unroll
    for (int n = 0; n < 2; ++n) {
      const int gn = nBase + wn * 32 + n * 16 + l15;
      const float bb = bias ? bias[gn] : 0.f;
#pragma unroll
      for (int r4 = 0; r4 < 4; ++r4) {
        const int gm = mBase + wm * 64 + m * 16 + l4 * 4 + r4;
        float val = acc[m][n][r4] + bb;
        if (MODE == 0) {
          ((unsigned short*)C)[(size_t)gm * ND + gn] = f2bf(val);
        } else {
          val += resid[(size_t)gm * ND + gn];
          ((float*)C)[(size_t)gm * ND + gn] = val;
        }
      }
    }
}

// Fused QKV projection, A from f32 (conversion fused into staging).
// Grid 768 (= 8 XCDs x 96), bijective chunked swizzle: each XCD gets 8 m-panels.
__global__ __launch_bounds__(512) void gemm_qkv(
    const float* __restrict__ Q, const float* __restrict__ K,
    const float* __restrict__ V, const unsigned short* __restrict__ Wqb,
    const unsigned short* __restrict__ Wkb, const unsigned short* __restrict__ Wvb,
    const float* __restrict__ bq, const float* __restrict__ bk,
    const float* __restrict__ bv, unsigned short* __restrict__ qo,
    unsigned short* __restrict__ ko, unsigned short* __restrict__ vo) {
  const int bid = blockIdx.x;
  const int lid = (bid & 7) * 96 + (bid >> 3);
  const int by = lid / 12, bx = lid % 12;
  const int seg = bx >> 2, nloc = bx & 3;
  const float* A = seg == 0 ? Q : seg == 1 ? K : V;
  const unsigned short* W = seg == 0 ? Wqb : seg == 1 ? Wkb : Wvb;
  const float* bias = seg == 0 ? bq : seg == 1 ? bk : bv;
  unsigned short* C = seg == 0 ? qo : seg == 1 ? ko : vo;
  gemm_tile<true, 0>(A, W, bias, nullptr, C, by * 128, nloc * 128);
}

// Wo GEMM + bias + residual(Q): grid 256 (= 8 x 32), chunked swizzle.
__global__ __launch_bounds__(512) void gemm_wo(const unsigned short* __restrict__ ctx,
                                               const unsigned short* __restrict__ Wob,
                                               const float* __restrict__ bo,
                                               const float* __restrict__ Qres,
                                               float* __restrict__ out) {
  const int bid = blockIdx.x;
  const int lid = (bid & 7) * 32 + (bid >> 3);
  const int by = lid >> 2, bx = lid & 3;
  gemm_tile<false, 1>(ctx, Wob, bo, Qres, out, by * 128, bx * 128);
}

// ---- attention: one wave per (b,h); lane -> (i=lane>>3, j=lane&7)
__global__ __launch_bounds__(256) void attn_kernel(
    const unsigned short* __restrict__ q, const unsigned short* __restrict__ k,
    const unsigned short* __restrict__ v, const int* __restrict__ mask,
    const float* __restrict__ hyper, float* __restrict__ wout,
    unsigned short* __restrict__ ctx) {
  const int tid = threadIdx.x;
  const int wid = tid >> 6, lane = tid & 63;
  const int t = blockIdx.x * 4 + wid;  // b*16 + h
  const int b = t >> 4, h = t & 15;
  const int i = lane >> 3, j = lane & 7;

  const unsigned short* qrow = q + (size_t)(b * 8 + i) * ND + h * 32;
  const unsigned short* krow = k + (size_t)(b * 8 + j) * ND + h * 32;
  float dot = 0.f;
#pragma unroll
  for (int c = 0; c < 4; ++c) {
    const short8 qv = ((const short8*)qrow)[c];
    const short8 kv = ((const short8*)krow)[c];
#pragma unroll
    for (int e = 0; e < 8; ++e)
      dot += bf2f((unsigned short)qv[e]) * bf2f((unsigned short)kv[e]);
  }
  float score = dot * 0.17677669529663687f;  // 1/sqrt(32)
  if (mask[b * 64 + i * 8 + j]) score = -1e9f;

  float mx = score;
#pragma unroll
  for (int o = 4; o; o >>= 1) mx = fmaxf(mx, __shfl_xor(mx, o, 8));
  const float e = __expf(score - mx);
  float sm = e;
#pragma unroll
  for (int o = 4; o; o >>= 1) sm += __shfl_xor(sm, o, 8);
  const float w = e / sm;
  wout[(size_t)t * 64 + lane] = w;

  const int d0 = (lane & 7) * 4;
  float c0 = 0, c1 = 0, c2 = 0, c3 = 0;
#pragma unroll
  for (int jj = 0; jj < 8; ++jj) {
    const float wj = __shfl(w, jj, 8);
    const ushort4v vv = *(const ushort4v*)(v + (size_t)(b * 8 + jj) * ND + h * 32 + d0);
    c0 += wj * bf2f(vv[0]); c1 += wj * bf2f(vv[1]);
    c2 += wj * bf2f(vv[2]); c3 += wj * bf2f(vv[3]);
  }
  const float4 hv = *(const float4*)(hyper + (size_t)b * 4096 + h * 256 + i * 32 + d0);
  ushort4v co;
  co[0] = f2bf(c0 * hv.x); co[1] = f2bf(c1 * hv.y);
  co[2] = f2bf(c2 * hv.z); co[3] = f2bf(c3 * hv.w);
  *(ushort4v*)(ctx + (size_t)(b * 8 + i) * ND + h * 32 + d0) = co;
}

// ---- in-place: io = LN(io) * g + b  (residual+bias already fused into gemm_wo)
__global__ __launch_bounds__(256) void ln_kernel(float* __restrict__ io,
                                                 const float* __restrict__ g,
                                                 const float* __restrict__ be) {
  const int tid = threadIdx.x, wid = tid >> 6, lane = tid & 63;
  const size_t row = (size_t)blockIdx.x * 4 + wid;
  float* prow = io + row * ND + lane * 8;
  float4 x0 = ((float4*)prow)[0], x1 = ((float4*)prow)[1];
  float s = x0.x + x0.y + x0.z + x0.w + x1.x + x1.y + x1.z + x1.w;
  float sq = x0.x * x0.x + x0.y * x0.y + x0.z * x0.z + x0.w * x0.w +
             x1.x * x1.x + x1.y * x1.y + x1.z * x1.z + x1.w * x1.w;
#pragma unroll
  for (int o = 32; o; o >>= 1) {
    s += __shfl_xor(s, o, 64);
    sq += __shfl_xor(sq, o, 64);
  }
  const float mu = s * (1.f / 512.f);
  const float inv = rsqrtf(sq * (1.f / 512.f) - mu * mu + 1e-5f);
  const float4 g0 = ((const float4*)(g + lane * 8))[0];
  const float4 g1 = ((const float4*)(g + lane * 8))[1];
  const float4 e0 = ((const float4*)(be + lane * 8))[0];
  const float4 e1 = ((const float4*)(be + lane * 8))[1];
  float4 o0, o1;
  o0.x = (x0.x - mu) * inv * g0.x + e0.x; o0.y = (x0.y - mu) * inv * g0.y + e0.y;
  o0.z = (x0.z - mu) * inv * g0.z + e0.z; o0.w = (x0.w - mu) * inv * g0.w + e0.w;
  o1.x = (x1.x - mu) * inv * g1.x + e1.x; o1.y = (x1.y - mu) * inv * g1.y + e1.y;
  o1.z = (x1.z - mu) * inv * g1.z + e1.z; o1.w = (x1.w - mu) * inv * g1.w + e1.w;
  ((float4*)prow)[0] = o0;
  ((float4*)prow)[1] = o1;
}

extern "C" void kernel_launch(void* const* d_in, const int* in_sizes, int n_in,
                              void* d_out, int out_size, void* d_ws, size_t ws_size,
                              hipStream_t stream) {
  const float* Q = (const float*)d_in[0];
  const float* K = (const float*)d_in[1];
  const float* V = (const float*)d_in[2];
  const int* msk = (const int*)d_in[3];
  const float* hyper = (const float*)d_in[4];
  const float* Wq = (const float*)d_in[5];
  const float* bq = (const float*)d_in[6];
  const float* Wk = (const float*)d_in[7];
  const float* bk = (const float*)d_in[8];
  const float* Wv = (const float*)d_in[9];
  const float* bv = (const float*)d_in[10];
  const float* Wo = (const float*)d_in[11];
  const float* bo = (const float*)d_in[12];
  const float* lg = (const float*)d_in[13];
  const float* lb = (const float*)d_in[14];

  float* out = (float*)d_out;           // [8192,512] fp32
  float* wout = out + (size_t)NM * ND;  // [1024,16,8,8] fp32

  const size_t MAT = (size_t)NM * ND;  // elements
  unsigned short* qb = (unsigned short*)d_ws;
  unsigned short* kb = qb + MAT;
  unsigned short* vb = kb + MAT;
  unsigned short* ctxb = vb + MAT;
  unsigned short* Wqb = ctxb + MAT;
  unsigned short* Wkb = Wqb + (size_t)ND * ND;
  unsigned short* Wvb = Wkb + (size_t)ND * ND;
  unsigned short* Wob = Wvb + (size_t)ND * ND;

  convert_w<<<512, 256, 0, stream>>>(Wq, Wk, Wv, Wo, Wqb, Wkb, Wvb, Wob);
  gemm_qkv<<<768, 512, 0, stream>>>(Q, K, V, Wqb, Wkb, Wvb,
                                    bq, bk, bv, qb, kb, vb);
  attn_kernel<<<4096, 256, 0, stream>>>(qb, kb, vb, msk, hyper, wout, ctxb);
  gemm_wo<<<256, 512, 0, stream>>>(ctxb, Wob, bo, Q, out);
  ln_kernel<<<2048, 256, 0, stream>>>(out, lg, lb);
}

// Round 5
// 72.974 us; speedup vs baseline: 1.1531x; 1.0228x over previous
//
#include <hip/hip_runtime.h>
#include <hip/hip_bf16.h>
#include <cstdint>

// Problem constants: B=1024, S=8, H=16, DK=DV=32, D=512
#define NB 1024
#define ND 512
#define NM 8192  // B*S rows

typedef __attribute__((ext_vector_type(8))) short short8;
typedef __attribute__((ext_vector_type(8))) __bf16 bf16x8;
typedef __attribute__((ext_vector_type(4))) float f32x4;
typedef __attribute__((ext_vector_type(4))) unsigned short ushort4v;

__device__ __forceinline__ unsigned short f2bf(float f) {
  uint32_t x = __builtin_bit_cast(uint32_t, f);
  x += 0x7fffu + ((x >> 16) & 1u);  // RNE
  return (unsigned short)(x >> 16);
}
__device__ __forceinline__ float bf2f(unsigned short u) {
  return __builtin_bit_cast(float, (uint32_t)u << 16);
}
__device__ __forceinline__ f32x4 mfma16(short8 a, short8 b, f32x4 c) {
  return __builtin_amdgcn_mfma_f32_16x16x32_bf16(
      __builtin_bit_cast(bf16x8, a), __builtin_bit_cast(bf16x8, b), c, 0, 0, 0);
}

// ---- fp32 -> bf16 pre-convert: weights only (Wq,Wk,Wv,Wo: 4 x 262144)
__global__ __launch_bounds__(256) void convert_w(
    const float* __restrict__ Wq, const float* __restrict__ Wk,
    const float* __restrict__ Wv, const float* __restrict__ Wo,
    unsigned short* __restrict__ Wqb, unsigned short* __restrict__ Wkb,
    unsigned short* __restrict__ Wvb, unsigned short* __restrict__ Wob) {
  const int idx = blockIdx.x * 256 + threadIdx.x;  // one 8-elem chunk each
  const int sel = idx >> 15, o = (idx & 32767) * 8;
  const float* src = sel == 0 ? Wq : sel == 1 ? Wk : sel == 2 ? Wv : Wo;
  unsigned short* dst = sel == 0 ? Wqb : sel == 1 ? Wkb : sel == 2 ? Wvb : Wob;
  const float4 a = ((const float4*)(src + o))[0];
  const float4 b = ((const float4*)(src + o))[1];
  short8 r;
  r[0] = (short)f2bf(a.x); r[1] = (short)f2bf(a.y);
  r[2] = (short)f2bf(a.z); r[3] = (short)f2bf(a.w);
  r[4] = (short)f2bf(b.x); r[5] = (short)f2bf(b.y);
  r[6] = (short)f2bf(b.z); r[7] = (short)f2bf(b.w);
  *(short8*)(dst + o) = r;
}

// Per-thread prefetch register set for one K-tile of staging.
// A_F32: a[4] holds raw f32 (cvt deferred to ds_write). else ab[2] bf16.
struct StageF32 { float4 a[4]; short8 w[2]; };
struct StageBF  { short8 ab[2]; short8 w[2]; };

// ---- GEMM tile core, T14 pipelined (issue loads for kt+1 before MFMA of kt):
// C[m][n] = A[m][:] . W[n][:] (+bias[, +resid])
// 128x128 tile, BK=64, 512 threads (8 waves 2x4, wave tile 64x32, acc 4x2).
// LDS XOR-swizzle byte ^= (row&7)<<4 on write AND read. Single LDS buffer,
// 2 barriers/K-iter; global-load latency hides under ds_read+MFMA phase.
// MODE 0: C = bf16(acc + bias).  MODE 1: C = f32(acc + bias + resid).
template <bool A_F32, int MODE>
__device__ __forceinline__ void gemm_tile(const void* __restrict__ A,
                                          const unsigned short* __restrict__ W,
                                          const float* __restrict__ bias,
                                          const float* __restrict__ resid,
                                          void* __restrict__ C, int mBase, int nBase) {
  __shared__ unsigned short As[128 * 64];
  __shared__ unsigned short Bs[128 * 64];
  const int tid = threadIdx.x;
  const int lane = tid & 63, wid = tid >> 6;
  const int wm = wid >> 2, wn = wid & 3;
  const int l15 = lane & 15, l4 = lane >> 4;
  // staging geometry: chunk i (i=0,1): logical byte Lb in 128x64 bf16 tile
  const int Lb0 = tid * 16, Lb1 = 8192 + tid * 16;
  const int r0 = Lb0 >> 7, c0 = (Lb0 & 127) >> 1, P0 = Lb0 ^ ((r0 & 7) << 4);
  const int r1 = Lb1 >> 7, c1 = (Lb1 & 127) >> 1, P1 = Lb1 ^ ((r1 & 7) << 4);

  f32x4 acc[4][2] = {};
  StageF32 sf, nf;
  StageBF sb, nb;

  // issue loads for K-tile kt into (sf|sb)
  auto issue = [&](int kt, StageF32& f, StageBF& bfs) {
    const int kBase = kt * 64;
    if (A_F32) {
      const float* s0 = (const float*)A + (size_t)(mBase + r0) * ND + kBase + c0;
      const float* s1 = (const float*)A + (size_t)(mBase + r1) * ND + kBase + c1;
      f.a[0] = ((const float4*)s0)[0]; f.a[1] = ((const float4*)s0)[1];
      f.a[2] = ((const float4*)s1)[0]; f.a[3] = ((const float4*)s1)[1];
      f.w[0] = *(const short8*)(W + (size_t)(nBase + r0) * ND + kBase + c0);
      f.w[1] = *(const short8*)(W + (size_t)(nBase + r1) * ND + kBase + c1);
    } else {
      bfs.ab[0] = *(const short8*)((const unsigned short*)A + (size_t)(mBase + r0) * ND + kBase + c0);
      bfs.ab[1] = *(const short8*)((const unsigned short*)A + (size_t)(mBase + r1) * ND + kBase + c1);
      bfs.w[0] = *(const short8*)(W + (size_t)(nBase + r0) * ND + kBase + c0);
      bfs.w[1] = *(const short8*)(W + (size_t)(nBase + r1) * ND + kBase + c1);
    }
  };
  // cvt (if f32) + swizzled ds_write of current stage regs
  auto write_lds = [&](StageF32& f, StageBF& bfs) {
    short8 av0, av1;
    if (A_F32) {
      av0[0] = (short)f2bf(f.a[0].x); av0[1] = (short)f2bf(f.a[0].y);
      av0[2] = (short)f2bf(f.a[0].z); av0[3] = (short)f2bf(f.a[0].w);
      av0[4] = (short)f2bf(f.a[1].x); av0[5] = (short)f2bf(f.a[1].y);
      av0[6] = (short)f2bf(f.a[1].z); av0[7] = (short)f2bf(f.a[1].w);
      av1[0] = (short)f2bf(f.a[2].x); av1[1] = (short)f2bf(f.a[2].y);
      av1[2] = (short)f2bf(f.a[2].z); av1[3] = (short)f2bf(f.a[2].w);
      av1[4] = (short)f2bf(f.a[3].x); av1[5] = (short)f2bf(f.a[3].y);
      av1[6] = (short)f2bf(f.a[3].z); av1[7] = (short)f2bf(f.a[3].w);
      *(short8*)((char*)As + P0) = av0;
      *(short8*)((char*)As + P1) = av1;
      *(short8*)((char*)Bs + P0) = f.w[0];
      *(short8*)((char*)Bs + P1) = f.w[1];
    } else {
      *(short8*)((char*)As + P0) = bfs.ab[0];
      *(short8*)((char*)As + P1) = bfs.ab[1];
      *(short8*)((char*)Bs + P0) = bfs.w[0];
      *(short8*)((char*)Bs + P1) = bfs.w[1];
    }
  };

  issue(0, sf, sb);
  for (int kt = 0; kt < 8; ++kt) {
    write_lds(sf, sb);   // s_waitcnt vmcnt for this tile's loads lands here
    __syncthreads();
    if (kt < 7) issue(kt + 1, nf, nb);  // overlap next loads w/ compute below
#pragma unroll
    for (int kk = 0; kk < 2; ++kk) {
      short8 af[4], bf4[2];
#pragma unroll
      for (int m = 0; m < 4; ++m) {
        const int r = wm * 64 + m * 16 + l15;
        const int Lb = r * 128 + kk * 64 + l4 * 16;
        af[m] = *(const short8*)((char*)As + (Lb ^ ((r & 7) << 4)));
      }
#pragma unroll
      for (int n = 0; n < 2; ++n) {
        const int r = wn * 32 + n * 16 + l15;
        const int Lb = r * 128 + kk * 64 + l4 * 16;
        bf4[n] = *(const short8*)((char*)Bs + (Lb ^ ((r & 7) << 4)));
      }
#pragma unroll
      for (int m = 0; m < 4; ++m)
#pragma unroll
        for (int n = 0; n < 2; ++n)
          acc[m][n] = mfma16(af[m], bf4[n], acc[m][n]);
    }
    __syncthreads();
    sf = nf;
    sb = nb;
  }

  // C/D layout: col = lane&15, row = (lane>>4)*4 + r  [verified rounds 1-4]
#pragma unroll
  for (int m = 0; m < 4; ++m)
#pragma unroll
    for (int n = 0; n < 2; ++n) {
      const int gn = nBase + wn * 32 + n * 16 + l15;
      const float bb = bias ? bias[gn] : 0.f;
#pragma unroll
      for (int r4 = 0; r4 < 4; ++r4) {
        const int gm = mBase + wm * 64 + m * 16 + l4 * 4 + r4;
        float val = acc[m][n][r4] + bb;
        if (MODE == 0) {
          ((unsigned short*)C)[(size_t)gm * ND + gn] = f2bf(val);
        } else {
          val += resid[(size_t)gm * ND + gn];
          ((float*)C)[(size_t)gm * ND + gn] = val;
        }
      }
    }
}

// Fused QKV projection, A from f32 (conversion fused into staging).
// Grid 768 (= 8 XCDs x 96), bijective chunked swizzle. 3 blocks/CU target
// (launch_bounds caps VGPR at ~85 for 6 waves/SIMD).
__global__ __launch_bounds__(512, 6) void gemm_qkv(
    const float* __restrict__ Q, const float* __restrict__ K,
    const float* __restrict__ V, const unsigned short* __restrict__ Wqb,
    const unsigned short* __restrict__ Wkb, const unsigned short* __restrict__ Wvb,
    const float* __restrict__ bq, const float* __restrict__ bk,
    const float* __restrict__ bv, unsigned short* __restrict__ qo,
    unsigned short* __restrict__ ko, unsigned short* __restrict__ vo) {
  const int bid = blockIdx.x;
  const int lid = (bid & 7) * 96 + (bid >> 3);
  const int by = lid / 12, bx = lid % 12;
  const int seg = bx >> 2, nloc = bx & 3;
  const float* A = seg == 0 ? Q : seg == 1 ? K : V;
  const unsigned short* W = seg == 0 ? Wqb : seg == 1 ? Wkb : Wvb;
  const float* bias = seg == 0 ? bq : seg == 1 ? bk : bv;
  unsigned short* C = seg == 0 ? qo : seg == 1 ? ko : vo;
  gemm_tile<true, 0>(A, W, bias, nullptr, C, by * 128, nloc * 128);
}

// Wo GEMM + bias + residual(Q): grid 256 (1 block/CU), chunked swizzle.
__global__ __launch_bounds__(512, 2) void gemm_wo(const unsigned short* __restrict__ ctx,
                                                  const unsigned short* __restrict__ Wob,
                                                  const float* __restrict__ bo,
                                                  const float* __restrict__ Qres,
                                                  float* __restrict__ out) {
  const int bid = blockIdx.x;
  const int lid = (bid & 7) * 32 + (bid >> 3);
  const int by = lid >> 2, bx = lid & 3;
  gemm_tile<false, 1>(ctx, Wob, bo, Qres, out, by * 128, bx * 128);
}

// ---- attention: one wave per (b,h); lane -> (i=lane>>3, j=lane&7)
__global__ __launch_bounds__(256) void attn_kernel(
    const unsigned short* __restrict__ q, const unsigned short* __restrict__ k,
    const unsigned short* __restrict__ v, const int* __restrict__ mask,
    const float* __restrict__ hyper, float* __restrict__ wout,
    unsigned short* __restrict__ ctx) {
  const int tid = threadIdx.x;
  const int wid = tid >> 6, lane = tid & 63;
  const int t = blockIdx.x * 4 + wid;  // b*16 + h
  const int b = t >> 4, h = t & 15;
  const int i = lane >> 3, j = lane & 7;

  const unsigned short* qrow = q + (size_t)(b * 8 + i) * ND + h * 32;
  const unsigned short* krow = k + (size_t)(b * 8 + j) * ND + h * 32;
  float dot = 0.f;
#pragma unroll
  for (int c = 0; c < 4; ++c) {
    const short8 qv = ((const short8*)qrow)[c];
    const short8 kv = ((const short8*)krow)[c];
#pragma unroll
    for (int e = 0; e < 8; ++e)
      dot += bf2f((unsigned short)qv[e]) * bf2f((unsigned short)kv[e]);
  }
  float score = dot * 0.17677669529663687f;  // 1/sqrt(32)
  if (mask[b * 64 + i * 8 + j]) score = -1e9f;

  float mx = score;
#pragma unroll
  for (int o = 4; o; o >>= 1) mx = fmaxf(mx, __shfl_xor(mx, o, 8));
  const float e = __expf(score - mx);
  float sm = e;
#pragma unroll
  for (int o = 4; o; o >>= 1) sm += __shfl_xor(sm, o, 8);
  const float w = e / sm;
  wout[(size_t)t * 64 + lane] = w;

  const int d0 = (lane & 7) * 4;
  float c0 = 0, c1 = 0, c2 = 0, c3 = 0;
#pragma unroll
  for (int jj = 0; jj < 8; ++jj) {
    const float wj = __shfl(w, jj, 8);
    const ushort4v vv = *(const ushort4v*)(v + (size_t)(b * 8 + jj) * ND + h * 32 + d0);
    c0 += wj * bf2f(vv[0]); c1 += wj * bf2f(vv[1]);
    c2 += wj * bf2f(vv[2]); c3 += wj * bf2f(vv[3]);
  }
  const float4 hv = *(const float4*)(hyper + (size_t)b * 4096 + h * 256 + i * 32 + d0);
  ushort4v co;
  co[0] = f2bf(c0 * hv.x); co[1] = f2bf(c1 * hv.y);
  co[2] = f2bf(c2 * hv.z); co[3] = f2bf(c3 * hv.w);
  *(ushort4v*)(ctx + (size_t)(b * 8 + i) * ND + h * 32 + d0) = co;
}

// ---- in-place: io = LN(io) * g + b  (residual+bias already fused into gemm_wo)
__global__ __launch_bounds__(256) void ln_kernel(float* __restrict__ io,
                                                 const float* __restrict__ g,
                                                 const float* __restrict__ be) {
  const int tid = threadIdx.x, wid = tid >> 6, lane = tid & 63;
  const size_t row = (size_t)blockIdx.x * 4 + wid;
  float* prow = io + row * ND + lane * 8;
  float4 x0 = ((float4*)prow)[0], x1 = ((float4*)prow)[1];
  float s = x0.x + x0.y + x0.z + x0.w + x1.x + x1.y + x1.z + x1.w;
  float sq = x0.x * x0.x + x0.y * x0.y + x0.z * x0.z + x0.w * x0.w +
             x1.x * x1.x + x1.y * x1.y + x1.z * x1.z + x1.w * x1.w;
#pragma unroll
  for (int o = 32; o; o >>= 1) {
    s += __shfl_xor(s, o, 64);
    sq += __shfl_xor(sq, o, 64);
  }
  const float mu = s * (1.f / 512.f);
  const float inv = rsqrtf(sq * (1.f / 512.f) - mu * mu + 1e-5f);
  const float4 g0 = ((const float4*)(g + lane * 8))[0];
  const float4 g1 = ((const float4*)(g + lane * 8))[1];
  const float4 e0 = ((const float4*)(be + lane * 8))[0];
  const float4 e1 = ((const float4*)(be + lane * 8))[1];
  float4 o0, o1;
  o0.x = (x0.x - mu) * inv * g0.x + e0.x; o0.y = (x0.y - mu) * inv * g0.y + e0.y;
  o0.z = (x0.z - mu) * inv * g0.z + e0.z; o0.w = (x0.w - mu) * inv * g0.w + e0.w;
  o1.x = (x1.x - mu) * inv * g1.x + e1.x; o1.y = (x1.y - mu) * inv * g1.y + e1.y;
  o1.z = (x1.z - mu) * inv * g1.z + e1.z; o1.w = (x1.w - mu) * inv * g1.w + e1.w;
  ((float4*)prow)[0] = o0;
  ((float4*)prow)[1] = o1;
}

extern "C" void kernel_launch(void* const* d_in, const int* in_sizes, int n_in,
                              void* d_out, int out_size, void* d_ws, size_t ws_size,
                              hipStream_t stream) {
  const float* Q = (const float*)d_in[0];
  const float* K = (const float*)d_in[1];
  const float* V = (const float*)d_in[2];
  const int* msk = (const int*)d_in[3];
  const float* hyper = (const float*)d_in[4];
  const float* Wq = (const float*)d_in[5];
  const float* bq = (const float*)d_in[6];
  const float* Wk = (const float*)d_in[7];
  const float* bk = (const float*)d_in[8];
  const float* Wv = (const float*)d_in[9];
  const float* bv = (const float*)d_in[10];
  const float* Wo = (const float*)d_in[11];
  const float* bo = (const float*)d_in[12];
  const float* lg = (const float*)d_in[13];
  const float* lb = (const float*)d_in[14];

  float* out = (float*)d_out;           // [8192,512] fp32
  float* wout = out + (size_t)NM * ND;  // [1024,16,8,8] fp32

  const size_t MAT = (size_t)NM * ND;  // elements
  unsigned short* qb = (unsigned short*)d_ws;
  unsigned short* kb = qb + MAT;
  unsigned short* vb = kb + MAT;
  unsigned short* ctxb = vb + MAT;
  unsigned short* Wqb = ctxb + MAT;
  unsigned short* Wkb = Wqb + (size_t)ND * ND;
  unsigned short* Wvb = Wkb + (size_t)ND * ND;
  unsigned short* Wob = Wvb + (size_t)ND * ND;

  convert_w<<<512, 256, 0, stream>>>(Wq, Wk, Wv, Wo, Wqb, Wkb, Wvb, Wob);
  gemm_qkv<<<768, 512, 0, stream>>>(Q, K, V, Wqb, Wkb, Wvb,
                                    bq, bk, bv, qb, kb, vb);
  attn_kernel<<<4096, 256, 0, stream>>>(qb, kb, vb, msk, hyper, wout, ctxb);
  gemm_wo<<<256, 512, 0, stream>>>(ctxb, Wob, bo, Q, out);
  ln_kernel<<<2048, 256, 0, stream>>>(out, lg, lb);
}